// Round 11
// baseline (255.909 us; speedup 1.0000x reference)
//
#include <hip/hip_runtime.h>
#include <hip/hip_bf16.h>
#include <stdint.h>

#define D_MODEL 1024
#define NH 16
#define SEQ 512
#define DK 64
#define BATCH 16
#define M_TOT (BATCH*SEQ)   // 8192

typedef unsigned short u16;
typedef unsigned int u32;
typedef __attribute__((ext_vector_type(8))) __bf16 bf16x8;
typedef __attribute__((ext_vector_type(4))) u16 ushort4v;
typedef __attribute__((ext_vector_type(4))) float f32x4;

// round-half-up bf16 pack: 2 VALU ops; differs from RNE only on exact ties
static __device__ __forceinline__ u16 f2bf(float f) {
    union { float f; u32 i; } c; c.f = f;
    return (u16)((c.i + 0x8000u) >> 16);
}
static __device__ __forceinline__ u32 cvtpk(float lo, float hi) {  // 2xf32 -> packed bf16x2
    u32 r; asm("v_cvt_pk_bf16_f32 %0, %1, %2" : "=v"(r) : "v"(lo), "v"(hi)); return r;
}
static __device__ __forceinline__ void async_copy16(const void* g, void* l) {
    __builtin_amdgcn_global_load_lds(
        (const __attribute__((address_space(1))) u32*)g,
        (__attribute__((address_space(3))) u32*)l, 16, 0, 0);
}
static __device__ __forceinline__ float fexp2(float x) {   // v_exp_f32 = 2^x
    float r; asm("v_exp_f32 %0, %1" : "=v"(r) : "v"(x)); return r;
}

// ---- prep: x f32->bf16 convert (grid-stride, blocks 0..2047) + Wq/Wk/Wv transpose ----
__global__ __launch_bounds__(256) void prep(const float* __restrict__ x,
                                            u16* __restrict__ xbf,
                                            const float* __restrict__ Wq,
                                            const float* __restrict__ Wk,
                                            const float* __restrict__ Wv,
                                            u16* __restrict__ Wt3) {
    __shared__ u16 tile[64][65];
    const int bid = blockIdx.x;
    const int t = threadIdx.x;
    if (bid < 2048) {
        #pragma unroll
        for (int it = 0; it < 4; ++it) {
            const int i = (bid * 1024 + it * 256 + t) * 4;
            float4 v = *(const float4*)&x[i];
            ushort4v o;
            o[0] = f2bf(v.x); o[1] = f2bf(v.y); o[2] = f2bf(v.z); o[3] = f2bf(v.w);
            *(ushort4v*)&xbf[i] = o;
        }
        return;
    }
    const int tw = bid - 2048;
    const int z = tw >> 8;
    const float* W = (z == 0) ? Wq : (z == 1) ? Wk : Wv;
    const int n0 = (tw & 15) * 64, k0 = ((tw >> 4) & 15) * 64;
    #pragma unroll
    for (int p = 0; p < 16; ++p) {
        int idx = p * 256 + t;
        int r = idx >> 6, c = idx & 63;
        tile[r][c] = f2bf(W[(size_t)(k0 + r) * D_MODEL + (n0 + c)]);
    }
    __syncthreads();
    #pragma unroll
    for (int p = 0; p < 16; ++p) {
        int idx = p * 256 + t;
        int r = idx >> 6, c = idx & 63;
        Wt3[((size_t)z * D_MODEL + n0 + r) * D_MODEL + (k0 + c)] = tile[c][r];
    }
}

// ---------- QKV GEMM: 128x128 tile, BK=32, 16.9 KB LDS -> 8 blocks/CU (32 waves) ----------
// Same math/swizzle family as the proven BK=64 kernel; barrier count doubles but each
// full-drain stall now hides under 7 other resident blocks (m114 implicit overlap).
// sel=n0>>10: 0 -> q [b,h,s,d]; 1 -> k [b,h,s,d]; 2 -> v^T [b,h,d,s]
__global__ __launch_bounds__(256) void gemm_qkv32(const u16* __restrict__ A,
                                                  const u16* __restrict__ Bt,
                                                  const float* __restrict__ b0,
                                                  const float* __restrict__ b1,
                                                  const float* __restrict__ b2,
                                                  u16* __restrict__ o0,
                                                  u16* __restrict__ o1,
                                                  u16* __restrict__ o2) {
    __shared__ __attribute__((aligned(16))) u16 smem[8448];   // A 4096 + B 4096 u16; epi 64x132
    u16* Asm = smem;
    u16* Bsm = smem + 4096;
    const int t = threadIdx.x;
    const int m0 = blockIdx.y * 128, n0 = blockIdx.x * 128;
    const int lane = t & 63, w = t >> 6;
    const int lm = lane & 15, quad = lane >> 4;
    const int wm = w >> 1, wn = w & 1;

    f32x4 acc[4][4];
    #pragma unroll
    for (int i = 0; i < 4; ++i)
        #pragma unroll
        for (int j = 0; j < 4; ++j) acc[i][j] = (f32x4){0.f, 0.f, 0.f, 0.f};

    for (int kt = 0; kt < D_MODEL / 32; ++kt) {
        const int k0 = kt * 32;
        __syncthreads();
        #pragma unroll
        for (int i = 0; i < 2; ++i) {      // A: 512 chunks of 16B (128 rows x 4 chunks)
            int chunk = i * 256 + t;
            int row = chunk >> 2, c = chunk & 3;
            int cs = c ^ (row & 3);        // XOR chunk swizzle (2-bit space at BK=32)
            async_copy16(A + (size_t)(m0 + row) * D_MODEL + k0 + cs * 8, &Asm[chunk * 8]);
        }
        #pragma unroll
        for (int i = 0; i < 2; ++i) {      // B: 512 chunks
            int chunk = i * 256 + t;
            int row = chunk >> 2, c = chunk & 3;
            int cs = c ^ (row & 3);
            async_copy16(Bt + (size_t)(n0 + row) * D_MODEL + k0 + cs * 8, &Bsm[chunk * 8]);
        }
        __syncthreads();
        // single k-step (K=32): fragment chunk = quad ^ (row&3)
        bf16x8 af[4], bfv[4];
        #pragma unroll
        for (int im = 0; im < 4; ++im) {
            const int row = wm * 64 + im * 16 + lm;
            const int c = quad ^ (row & 3);
            af[im] = *(const bf16x8*)&Asm[row * 32 + c * 8];
        }
        #pragma unroll
        for (int in = 0; in < 4; ++in) {
            const int row = wn * 64 + in * 16 + lm;
            const int c = quad ^ (row & 3);
            bfv[in] = *(const bf16x8*)&Bsm[row * 32 + c * 8];
        }
        #pragma unroll
        for (int im = 0; im < 4; ++im)
            #pragma unroll
            for (int in = 0; in < 4; ++in)
                acc[im][in] = __builtin_amdgcn_mfma_f32_16x16x32_bf16(
                    af[im], bfv[in], acc[im][in], 0, 0, 0);
    }

    __syncthreads();   // all MFMA LDS reads done; smem free for epilogue reuse
    const int sel = n0 >> 10;   // uniform per block
    if (sel == 2) {
        #pragma unroll
        for (int in = 0; in < 4; ++in) {
            const int nn = (n0 & 1023) + wn * 64 + in * 16 + lm;
            const float bv = b2[nn];
            const int h = nn >> 6, d = nn & 63;
            #pragma unroll
            for (int im = 0; im < 4; ++im) {
                const int mb = m0 + wm * 64 + im * 16 + quad * 4;
                const int b = mb >> 9, s = mb & 511;
                ushort4v pk;
                #pragma unroll
                for (int r = 0; r < 4; ++r) pk[r] = f2bf(acc[im][in][r] + bv);
                *(ushort4v*)&o2[((size_t)(b * NH + h) * DK + d) * SEQ + s] = pk;
            }
        }
    } else {
        u16* dst = sel ? o1 : o0;
        const float* bb = sel ? b1 : b0;
        u16 (*Cs)[132] = (u16(*)[132])smem;   // 64 x 132 u16 = 16.9 KB per pass
        #pragma unroll
        for (int ph = 0; ph < 2; ++ph) {      // 64-row passes (waves with wm==ph)
            if (wm == ph) {
                #pragma unroll
                for (int in = 0; in < 4; ++in) {
                    const int nl = wn * 64 + in * 16 + lm;
                    const float bv = bb[(n0 & 1023) + nl];
                    #pragma unroll
                    for (int im = 0; im < 4; ++im)
                        #pragma unroll
                        for (int r = 0; r < 4; ++r)
                            Cs[im * 16 + quad * 4 + r][nl] = f2bf(acc[im][in][r] + bv);
                }
            }
            __syncthreads();
            const int rr = t >> 2, hh = t & 3;   // 64 rows x 4 chunks of 32 u16 (64B)
            const int m = m0 + ph * 64 + rr;
            const int b = m >> 9, s = m & 511;
            const int h = ((n0 & 1023) >> 6) + (hh >> 1);
            u16* dp = &dst[((size_t)(b * NH + h) * SEQ + s) * DK + (hh & 1) * 32];
            #pragma unroll
            for (int c = 0; c < 4; ++c)
                *(uint4*)&dp[c * 8] = *(const uint4*)&Cs[rr][hh * 32 + c * 8];
            __syncthreads();
        }
    }
}

// ------------- out-projection GEMM (proven r7 128x128 BK=64 kernel) -------------
__global__ __launch_bounds__(256) void gemm_bt(const u16* __restrict__ A,
                                               const u16* __restrict__ Bt,
                                               const float* __restrict__ b0,
                                               void* __restrict__ o0) {
    __shared__ __attribute__((aligned(16))) u16 smem[16896];
    u16* Asm = smem;
    u16* Bsm = smem + 8192;
    const int t = threadIdx.x;
    const int m0 = blockIdx.y * 128, n0 = blockIdx.x * 128;
    const int lane = t & 63, w = t >> 6;
    const int lm = lane & 15, quad = lane >> 4;
    const int wm = w >> 1, wn = w & 1;

    f32x4 acc[4][4];
    #pragma unroll
    for (int i = 0; i < 4; ++i)
        #pragma unroll
        for (int j = 0; j < 4; ++j) acc[i][j] = (f32x4){0.f, 0.f, 0.f, 0.f};

    for (int kt = 0; kt < D_MODEL / 64; ++kt) {
        const int k0 = kt * 64;
        __syncthreads();
        #pragma unroll
        for (int i = 0; i < 4; ++i) {
            int chunk = i * 256 + t;
            int row = chunk >> 3, c = chunk & 7;
            int cs = c ^ (row & 7);
            async_copy16(A + (size_t)(m0 + row) * D_MODEL + k0 + cs * 8, &Asm[chunk * 8]);
        }
        #pragma unroll
        for (int i = 0; i < 4; ++i) {
            int chunk = i * 256 + t;
            int row = chunk >> 3, c = chunk & 7;
            int cs = c ^ (row & 7);
            async_copy16(Bt + (size_t)(n0 + row) * D_MODEL + k0 + cs * 8, &Bsm[chunk * 8]);
        }
        __syncthreads();
        #pragma unroll
        for (int ks = 0; ks < 64; ks += 32) {
            const int cbase = ks >> 3;
            bf16x8 af[4], bfv[4];
            #pragma unroll
            for (int im = 0; im < 4; ++im) {
                const int row = wm * 64 + im * 16 + lm;
                const int c = (cbase + quad) ^ (row & 7);
                af[im] = *(const bf16x8*)&Asm[row * 64 + c * 8];
            }
            #pragma unroll
            for (int in = 0; in < 4; ++in) {
                const int row = wn * 64 + in * 16 + lm;
                const int c = (cbase + quad) ^ (row & 7);
                bfv[in] = *(const bf16x8*)&Bsm[row * 64 + c * 8];
            }
            #pragma unroll
            for (int im = 0; im < 4; ++im)
                #pragma unroll
                for (int in = 0; in < 4; ++in)
                    acc[im][in] = __builtin_amdgcn_mfma_f32_16x16x32_bf16(
                        af[im], bfv[in], acc[im][in], 0, 0, 0);
        }
    }

    __syncthreads();
    float (*Cs)[132] = (float(*)[132])smem;
    #pragma unroll
    for (int ph = 0; ph < 2; ++ph) {
        if (wm == ph) {
            #pragma unroll
            for (int in = 0; in < 4; ++in) {
                const int nl = wn * 64 + in * 16 + lm;
                const float bv = b0[n0 + nl];
                #pragma unroll
                for (int im = 0; im < 4; ++im)
                    #pragma unroll
                    for (int r = 0; r < 4; ++r)
                        Cs[im * 16 + quad * 4 + r][nl] = acc[im][in][r] + bv;
            }
        }
        __syncthreads();
        const int rr = t >> 2, qq = t & 3;
        float* dp = &((float*)o0)[(size_t)(m0 + ph * 64 + rr) * D_MODEL + n0 + qq * 32];
        #pragma unroll
        for (int c = 0; c < 8; ++c)
            *(uint4*)&dp[c * 4] = *(const uint4*)&Cs[rr][qq * 32 + c * 4];
        __syncthreads();
    }
}

// -------- flash attention (r7-verbatim): block = (b, h, 128-row q tile); out FLAT --------
__global__ __launch_bounds__(256) void attn_flash(const u16* __restrict__ qg,
                                                  const u16* __restrict__ kg,
                                                  const u16* __restrict__ vTg,
                                                  const float* __restrict__ rel,
                                                  u16* __restrict__ aout,
                                                  const float* __restrict__ Wo,
                                                  u16* __restrict__ WtO) {
    // [kt 2x8KB][vt 2x8KB][biasb 2.5KB][U: qt 16KB / Pl 18KB] = 53760 B -> 3 blocks/CU
    __shared__ __attribute__((aligned(16))) char smem_raw[53760];
    u16* ktb = (u16*)smem_raw;                       // kt[2][64*64]
    u16* vtb = (u16*)(smem_raw + 16384);             // vt[2][64*64]
    float* biasb = (float*)(smem_raw + 32768);       // 640 f32 (pre-scaled by log2e)
    u16* qt = (u16*)(smem_raw + 35328);              // 128*64 u16, overlaid by Pl
    u16 (*Pl)[32][72] = (u16(*)[32][72])(smem_raw + 35328);   // [4 waves][32 q][64+8]

    const int t = threadIdx.x;
    const int F = blockIdx.x;
    if (F >= 1024) {   // ---- Wo transpose tail blocks ----
        u16 (*tile)[65] = (u16(*)[65])smem_raw;
        const int tw = F - 1024;
        const int n0 = (tw & 15) * 64, k0 = (tw >> 4) * 64;
        #pragma unroll
        for (int p = 0; p < 16; ++p) {
            int idx = p * 256 + t;
            int r = idx >> 6, c = idx & 63;
            tile[r][c] = f2bf(Wo[(size_t)(k0 + r) * D_MODEL + (n0 + c)]);
        }
        __syncthreads();
        #pragma unroll
        for (int p = 0; p < 16; ++p) {
            int idx = p * 256 + t;
            int r = idx >> 6, c = idx & 63;
            WtO[(size_t)(n0 + r) * D_MODEL + (k0 + c)] = tile[c][r];
        }
        return;
    }

    const int lane = t & 63, w = t >> 6;
    const int lm = lane & 15, quad = lane >> 4;
    const int xcd = F & 7, qti = (F >> 3) & 3, grp = F >> 5;
    const int p = grp * 8 + xcd;
    const int h = p & 15, b = p >> 4;
    const int q0 = qti * 128;
    const size_t bh = (size_t)(b * NH + h);
    const u16* qb = qg + bh * SEQ * DK;
    const u16* kb = kg + bh * SEQ * DK;
    const u16* vb = vTg + bh * DK * SEQ;

    #pragma unroll
    for (int i = 0; i < 2; ++i) {
        const int chunk = i * 256 + t, row = chunk >> 3, c = chunk & 7;
        const int cs = c ^ (row & 7);
        async_copy16(kb + row * DK + cs * 8, &ktb[chunk * 8]);
        async_copy16(vb + row * SEQ + cs * 8, &vtb[chunk * 8]);
    }

    #pragma unroll
    for (int i = 0; i < 4; ++i) {
        const int chunk = i * 256 + t, row = chunk >> 3, c = chunk & 7;
        const int cs = c ^ (row & 7);
        *(uint4*)&qt[chunk * 8] = *(const uint4*)&qb[(q0 + row) * DK + cs * 8];
    }
    for (int u = t; u < 639; u += 256) biasb[u] = rel[(q0 + u) * NH + h] * 1.44269504f;

    __syncthreads();

    bf16x8 aq[2][2];
    #pragma unroll
    for (int g = 0; g < 2; ++g) {
        const int ra = w * 32 + g * 16 + lm;
        aq[g][0] = *(const bf16x8*)&qt[ra * 64 + ((quad) ^ (ra & 7)) * 8];
        aq[g][1] = *(const bf16x8*)&qt[ra * 64 + ((4 + quad) ^ (ra & 7)) * 8];
    }
    __syncthreads();

    bf16x8 ones;
    #pragma unroll
    for (int i = 0; i < 8; ++i) ones[i] = (__bf16)1.0f;

    f32x4 ol[2];
    f32x4 o[2][4];
    #pragma unroll
    for (int g = 0; g < 2; ++g) {
        ol[g] = (f32x4){0.f, 0.f, 0.f, 0.f};
        #pragma unroll
        for (int sd = 0; sd < 4; ++sd) o[g][sd] = (f32x4){0.f, 0.f, 0.f, 0.f};
    }

    const float scale2 = 0.125f * 1.44269504f;

    for (int jt = 0; jt < 8; ++jt) {
        if (jt) __syncthreads();
        const int cur = jt & 1, nxt = cur ^ 1;
        u16* ktc = ktb + cur * 4096;
        u16* vtc = vtb + cur * 4096;
        if (jt < 7) {
            const int j1 = (jt + 1) * 64;
            u16* ktn = ktb + nxt * 4096;
            u16* vtn = vtb + nxt * 4096;
            #pragma unroll
            for (int i = 0; i < 2; ++i) {
                const int chunk = i * 256 + t, row = chunk >> 3, c = chunk & 7;
                const int cs = c ^ (row & 7);
                async_copy16(kb + (j1 + row) * DK + cs * 8, &ktn[chunk * 8]);
                async_copy16(vb + row * SEQ + j1 + cs * 8, &vtn[chunk * 8]);
            }
        }
        const int j0 = jt * 64;

        #pragma unroll
        for (int js = 0; js < 4; ++js) {
            const int rb = js * 16 + lm;
            bf16x8 bk0 = *(const bf16x8*)&ktc[rb * 64 + ((quad) ^ (rb & 7)) * 8];
            bf16x8 bk1 = *(const bf16x8*)&ktc[rb * 64 + ((4 + quad) ^ (rb & 7)) * 8];
            #pragma unroll
            for (int g = 0; g < 2; ++g) {
                f32x4 c = (f32x4){0.f, 0.f, 0.f, 0.f};
                c = __builtin_amdgcn_mfma_f32_16x16x32_bf16(bk0, aq[g][0], c, 0, 0, 0);
                c = __builtin_amdgcn_mfma_f32_16x16x32_bf16(bk1, aq[g][1], c, 0, 0, 0);
                const int bb0 = w * 32 + g * 16 + lm + 511 - j0 - js * 16 - quad * 4;
                float e0 = fexp2(c[0] * scale2 + biasb[bb0]);
                float e1 = fexp2(c[1] * scale2 + biasb[bb0 - 1]);
                float e2 = fexp2(c[2] * scale2 + biasb[bb0 - 2]);
                float e3 = fexp2(c[3] * scale2 + biasb[bb0 - 3]);
                uint2 pk = {cvtpk(e0, e1), cvtpk(e2, e3)};
                *(uint2*)&Pl[w][g * 16 + lm][js * 16 + quad * 4] = pk;
            }
        }

        bf16x8 ap[2][2];
        #pragma unroll
        for (int g = 0; g < 2; ++g) {
            ap[g][0] = *(const bf16x8*)&Pl[w][g * 16 + lm][quad * 8];
            ap[g][1] = *(const bf16x8*)&Pl[w][g * 16 + lm][32 + quad * 8];
            ol[g] = __builtin_amdgcn_mfma_f32_16x16x32_bf16(ones, ap[g][0], ol[g], 0, 0, 0);
            ol[g] = __builtin_amdgcn_mfma_f32_16x16x32_bf16(ones, ap[g][1], ol[g], 0, 0, 0);
        }
        #pragma unroll
        for (int sd = 0; sd < 4; ++sd) {
            const int rv = sd * 16 + lm;
            bf16x8 bv0 = *(const bf16x8*)&vtc[rv * 64 + ((quad) ^ (rv & 7)) * 8];
            bf16x8 bv1 = *(const bf16x8*)&vtc[rv * 64 + ((4 + quad) ^ (rv & 7)) * 8];
            #pragma unroll
            for (int g = 0; g < 2; ++g) {
                o[g][sd] = __builtin_amdgcn_mfma_f32_16x16x32_bf16(bv0, ap[g][0], o[g][sd], 0, 0, 0);
                o[g][sd] = __builtin_amdgcn_mfma_f32_16x16x32_bf16(bv1, ap[g][1], o[g][sd], 0, 0, 0);
            }
        }
    }

    #pragma unroll
    for (int g = 0; g < 2; ++g) {
        const float rinv = 1.0f / ol[g][0];
        #pragma unroll
        for (int sd = 0; sd < 4; ++sd) {
            uint2 pk = {cvtpk(o[g][sd][0] * rinv, o[g][sd][1] * rinv),
                        cvtpk(o[g][sd][2] * rinv, o[g][sd][3] * rinv)};
            *(uint2*)&Pl[w][g * 16 + lm][sd * 16 + quad * 4] = pk;
        }
    }
    const int rowl = lane >> 1, ch = lane & 1;
    u16* dp = aout + (size_t)(b * SEQ + q0 + w * 32 + rowl) * D_MODEL + h * DK + ch * 32;
    #pragma unroll
    for (int c = 0; c < 4; ++c)
        *(uint4*)&dp[c * 8] = *(const uint4*)&Pl[w][rowl][ch * 32 + c * 8];
}

extern "C" void kernel_launch(void* const* d_in, const int* in_sizes, int n_in,
                              void* d_out, int out_size, void* d_ws, size_t ws_size,
                              hipStream_t stream) {
    const float* x   = (const float*)d_in[0];
    const float* Wq  = (const float*)d_in[2];
    const float* bq  = (const float*)d_in[3];
    const float* Wk  = (const float*)d_in[4];
    const float* bk  = (const float*)d_in[5];
    const float* Wv  = (const float*)d_in[6];
    const float* bv  = (const float*)d_in[7];
    const float* Wo  = (const float*)d_in[8];
    const float* bo  = (const float*)d_in[9];
    const float* rel = (const float*)d_in[10];
    float* out = (float*)d_out;

    u16* ws = (u16*)d_ws;
    const size_t WSZ = (size_t)D_MODEL * D_MODEL;   // 1M u16 (2 MB)
    const size_t TSZ = (size_t)M_TOT * D_MODEL;     // 8M u16 (16 MB)
    u16* Wt3 = ws;            // 6 MB (qkv concat); slab0 reused for Wo^T (attn tail)
    u16* xbf = Wt3 + 3 * WSZ;
    u16* qws = xbf + TSZ;
    u16* kws = qws + TSZ;
    u16* vws = kws + TSZ;     // stored transposed [b,h,d,s]
    u16* aws = xbf;           // xbf dead after qkv GEMM; attn out FLAT [M, D_MODEL]

    dim3 tb(256);
    prep<<<dim3(2048 + 768), tb, 0, stream>>>(x, xbf, Wq, Wk, Wv, Wt3);
    gemm_qkv32<<<dim3(24, 64), tb, 0, stream>>>(xbf, Wt3, bq, bk, bv, qws, kws, vws);
    attn_flash<<<dim3(1024 + 256), tb, 0, stream>>>(qws, kws, vws, rel, aws, Wo, Wt3);
    gemm_bt<<<dim3(8, 64), tb, 0, stream>>>(aws, Wt3, bo, (void*)out);
}

// Round 12
// 244.622 us; speedup vs baseline: 1.0461x; 1.0461x over previous
//
#include <hip/hip_runtime.h>
#include <hip/hip_bf16.h>
#include <stdint.h>

#define D_MODEL 1024
#define NH 16
#define SEQ 512
#define DK 64
#define BATCH 16
#define M_TOT (BATCH*SEQ)   // 8192

typedef unsigned short u16;
typedef unsigned int u32;
typedef __attribute__((ext_vector_type(8))) __bf16 bf16x8;
typedef __attribute__((ext_vector_type(4))) u16 ushort4v;
typedef __attribute__((ext_vector_type(4))) float f32x4;

// round-half-up bf16 pack: 2 VALU ops; differs from RNE only on exact ties
static __device__ __forceinline__ u16 f2bf(float f) {
    union { float f; u32 i; } c; c.f = f;
    return (u16)((c.i + 0x8000u) >> 16);
}
static __device__ __forceinline__ u32 cvtpk(float lo, float hi) {  // 2xf32 -> packed bf16x2
    u32 r; asm("v_cvt_pk_bf16_f32 %0, %1, %2" : "=v"(r) : "v"(lo), "v"(hi)); return r;
}
static __device__ __forceinline__ void async_copy16(const void* g, void* l) {
    __builtin_amdgcn_global_load_lds(
        (const __attribute__((address_space(1))) u32*)g,
        (__attribute__((address_space(3))) u32*)l, 16, 0, 0);
}
static __device__ __forceinline__ float fexp2(float x) {   // v_exp_f32 = 2^x
    float r; asm("v_exp_f32 %0, %1" : "=v"(r) : "v"(x)); return r;
}

// ---- prep: x f32->bf16 convert (grid-stride, blocks 0..2047) + Wq/Wk/Wv transpose ----
__global__ __launch_bounds__(256) void prep(const float* __restrict__ x,
                                            u16* __restrict__ xbf,
                                            const float* __restrict__ Wq,
                                            const float* __restrict__ Wk,
                                            const float* __restrict__ Wv,
                                            u16* __restrict__ Wt3) {
    __shared__ u16 tile[64][65];
    const int bid = blockIdx.x;
    const int t = threadIdx.x;
    if (bid < 2048) {
        #pragma unroll
        for (int it = 0; it < 4; ++it) {
            const int i = (bid * 1024 + it * 256 + t) * 4;
            float4 v = *(const float4*)&x[i];
            ushort4v o;
            o[0] = f2bf(v.x); o[1] = f2bf(v.y); o[2] = f2bf(v.z); o[3] = f2bf(v.w);
            *(ushort4v*)&xbf[i] = o;
        }
        return;
    }
    const int tw = bid - 2048;
    const int z = tw >> 8;
    const float* W = (z == 0) ? Wq : (z == 1) ? Wk : Wv;
    const int n0 = (tw & 15) * 64, k0 = ((tw >> 4) & 15) * 64;
    #pragma unroll
    for (int p = 0; p < 16; ++p) {
        int idx = p * 256 + t;
        int r = idx >> 6, c = idx & 63;
        tile[r][c] = f2bf(W[(size_t)(k0 + r) * D_MODEL + (n0 + c)]);
    }
    __syncthreads();
    #pragma unroll
    for (int p = 0; p < 16; ++p) {
        int idx = p * 256 + t;
        int r = idx >> 6, c = idx & 63;
        Wt3[((size_t)z * D_MODEL + n0 + r) * D_MODEL + (k0 + c)] = tile[c][r];
    }
}

// ------------- C[m,n] = A[m,:]·Bt[n,:] + bias[n]  (async BT GEMM, XOR-swizzled LDS) -------------
// A is row-contiguous [M, D_MODEL] bf16.
// qkv=1: N=3072 fused; sel=n0>>10: 0 -> q [b,h,s,d]; 1 -> k [b,h,s,d]; 2 -> v^T [b,h,d,s]
// qkv=0: out-projection; writes f32 [M, D_MODEL]
__global__ __launch_bounds__(256) void gemm_bt(const u16* __restrict__ A,
                                               const u16* __restrict__ Bt,
                                               const float* __restrict__ b0,
                                               const float* __restrict__ b1,
                                               const float* __restrict__ b2,
                                               void* __restrict__ o0,
                                               void* __restrict__ o1,
                                               void* __restrict__ o2,
                                               int qkv) {
    __shared__ __attribute__((aligned(16))) u16 smem[16896];
    u16* Asm = smem;
    u16* Bsm = smem + 8192;
    const int t = threadIdx.x;
    const int m0 = blockIdx.y * 128, n0 = blockIdx.x * 128;
    const int lane = t & 63, w = t >> 6;
    const int lm = lane & 15, quad = lane >> 4;
    const int wm = w >> 1, wn = w & 1;

    f32x4 acc[4][4];
    #pragma unroll
    for (int i = 0; i < 4; ++i)
        #pragma unroll
        for (int j = 0; j < 4; ++j) acc[i][j] = (f32x4){0.f, 0.f, 0.f, 0.f};

    for (int kt = 0; kt < D_MODEL / 64; ++kt) {
        const int k0 = kt * 64;
        __syncthreads();
        #pragma unroll
        for (int i = 0; i < 4; ++i) {
            int chunk = i * 256 + t;
            int row = chunk >> 3, c = chunk & 7;
            int cs = c ^ (row & 7);   // XOR swizzle
            async_copy16(A + (size_t)(m0 + row) * D_MODEL + k0 + cs * 8, &Asm[chunk * 8]);
        }
        #pragma unroll
        for (int i = 0; i < 4; ++i) {
            int chunk = i * 256 + t;
            int row = chunk >> 3, c = chunk & 7;
            int cs = c ^ (row & 7);
            async_copy16(Bt + (size_t)(n0 + row) * D_MODEL + k0 + cs * 8, &Bsm[chunk * 8]);
        }
        __syncthreads();
        #pragma unroll
        for (int ks = 0; ks < 64; ks += 32) {
            const int cbase = ks >> 3;
            bf16x8 af[4], bfv[4];
            #pragma unroll
            for (int im = 0; im < 4; ++im) {
                const int row = wm * 64 + im * 16 + lm;
                const int c = (cbase + quad) ^ (row & 7);
                af[im] = *(const bf16x8*)&Asm[row * 64 + c * 8];
            }
            #pragma unroll
            for (int in = 0; in < 4; ++in) {
                const int row = wn * 64 + in * 16 + lm;
                const int c = (cbase + quad) ^ (row & 7);
                bfv[in] = *(const bf16x8*)&Bsm[row * 64 + c * 8];
            }
            #pragma unroll
            for (int im = 0; im < 4; ++im)
                #pragma unroll
                for (int in = 0; in < 4; ++in)
                    acc[im][in] = __builtin_amdgcn_mfma_f32_16x16x32_bf16(
                        af[im], bfv[in], acc[im][in], 0, 0, 0);
        }
    }

    __syncthreads();   // all MFMA LDS reads done; smem free for epilogue reuse
    if (qkv) {
        const int sel = n0 >> 10;   // uniform per block
        if (sel == 2) {
            #pragma unroll
            for (int in = 0; in < 4; ++in) {
                const int nn = (n0 & 1023) + wn * 64 + in * 16 + lm;
                const float bv = b2[nn];
                const int h = nn >> 6, d = nn & 63;
                #pragma unroll
                for (int im = 0; im < 4; ++im) {
                    const int mb = m0 + wm * 64 + im * 16 + quad * 4;
                    const int b = mb >> 9, s = mb & 511;
                    ushort4v pk;
                    #pragma unroll
                    for (int r = 0; r < 4; ++r) pk[r] = f2bf(acc[im][in][r] + bv);
                    *(ushort4v*)&((u16*)o2)[((size_t)(b * NH + h) * DK + d) * SEQ + s] = pk;
                }
            }
        } else {
            u16* dst = sel ? (u16*)o1 : (u16*)o0;
            const float* bb = sel ? b1 : b0;
            u16 (*Cs)[132] = (u16(*)[132])smem;
            #pragma unroll
            for (int in = 0; in < 4; ++in) {
                const int nl = wn * 64 + in * 16 + lm;
                const float bv = bb[(n0 & 1023) + nl];
                #pragma unroll
                for (int im = 0; im < 4; ++im)
                    #pragma unroll
                    for (int r = 0; r < 4; ++r)
                        Cs[wm * 64 + im * 16 + quad * 4 + r][nl] =
                            f2bf(acc[im][in][r] + bv);
            }
            __syncthreads();
            const int rr = t >> 1, hh = t & 1;
            const int m = m0 + rr;
            const int b = m >> 9, s = m & 511;
            const int h = ((n0 & 1023) >> 6) + hh;
            u16* dp = &dst[((size_t)(b * NH + h) * SEQ + s) * DK];
            #pragma unroll
            for (int c = 0; c < 8; ++c)
                *(uint4*)&dp[c * 8] = *(const uint4*)&Cs[rr][hh * 64 + c * 8];
        }
    } else {
        float (*Cs)[132] = (float(*)[132])smem;
        #pragma unroll
        for (int ph = 0; ph < 2; ++ph) {
            if (wm == ph) {
                #pragma unroll
                for (int in = 0; in < 4; ++in) {
                    const int nl = wn * 64 + in * 16 + lm;
                    const float bv = b0[n0 + nl];
                    #pragma unroll
                    for (int im = 0; im < 4; ++im)
                        #pragma unroll
                        for (int r = 0; r < 4; ++r)
                            Cs[im * 16 + quad * 4 + r][nl] = acc[im][in][r] + bv;
                }
            }
            __syncthreads();
            const int rr = t >> 2, qq = t & 3;
            float* dp = &((float*)o0)[(size_t)(m0 + ph * 64 + rr) * D_MODEL + n0 + qq * 32];
            #pragma unroll
            for (int c = 0; c < 8; ++c)
                *(uint4*)&dp[c * 4] = *(const uint4*)&Cs[rr][qq * 32 + c * 4];
            __syncthreads();
        }
    }
}

// -------- flash attention: block = (b, h, 128-row q tile); output FLAT [b,s,h*64+d] --------
// Staged K/V (DMA double-buffered, XOR-swizzled). VALU backbone cut:
//   * P-pack via v_cvt_pk_bf16_f32 (1 op / 2 elems)
//   * row-sum lsum via MFMA with all-ones A operand (deletes adds + epilogue shuffles)
// LDS 52.5 KB -> 3 blocks/CU: qt (dead after Q-register hoist) overlaid with wave-private Pl.
// Blocks >= 1024 transpose Wo into Wt3 slab0 (dead after QKV).
__global__ __launch_bounds__(256) void attn_flash(const u16* __restrict__ qg,
                                                  const u16* __restrict__ kg,
                                                  const u16* __restrict__ vTg,
                                                  const float* __restrict__ rel,
                                                  u16* __restrict__ aout,
                                                  const float* __restrict__ Wo,
                                                  u16* __restrict__ WtO) {
    // [kt 2x8KB][vt 2x8KB][biasb 2.5KB][U: qt 16KB / Pl 18KB] = 53760 B -> 3 blocks/CU
    __shared__ __attribute__((aligned(16))) char smem_raw[53760];
    u16* ktb = (u16*)smem_raw;                       // kt[2][64*64]
    u16* vtb = (u16*)(smem_raw + 16384);             // vt[2][64*64]
    float* biasb = (float*)(smem_raw + 32768);       // 640 f32 (pre-scaled by log2e)
    u16* qt = (u16*)(smem_raw + 35328);              // 128*64 u16, overlaid by Pl
    u16 (*Pl)[32][72] = (u16(*)[32][72])(smem_raw + 35328);   // [4 waves][32 q][64+8]

    const int t = threadIdx.x;
    const int F = blockIdx.x;
    if (F >= 1024) {   // ---- Wo transpose tail blocks ----
        u16 (*tile)[65] = (u16(*)[65])smem_raw;
        const int tw = F - 1024;
        const int n0 = (tw & 15) * 64, k0 = (tw >> 4) * 64;
        #pragma unroll
        for (int p = 0; p < 16; ++p) {
            int idx = p * 256 + t;
            int r = idx >> 6, c = idx & 63;
            tile[r][c] = f2bf(Wo[(size_t)(k0 + r) * D_MODEL + (n0 + c)]);
        }
        __syncthreads();
        #pragma unroll
        for (int p = 0; p < 16; ++p) {
            int idx = p * 256 + t;
            int r = idx >> 6, c = idx & 63;
            WtO[(size_t)(n0 + r) * D_MODEL + (k0 + c)] = tile[c][r];
        }
        return;
    }

    const int lane = t & 63, w = t >> 6;
    const int lm = lane & 15, quad = lane >> 4;
    const int xcd = F & 7, qti = (F >> 3) & 3, grp = F >> 5;
    const int p = grp * 8 + xcd;          // (b,h) id; all 4 q-tiles share xcd -> L2 reuse
    const int h = p & 15, b = p >> 4;
    const int q0 = qti * 128;
    const size_t bh = (size_t)(b * NH + h);
    const u16* qb = qg + bh * SEQ * DK;
    const u16* kb = kg + bh * SEQ * DK;
    const u16* vb = vTg + bh * DK * SEQ;

    // preload jt=0 K/V into buffer 0 via DMA
    #pragma unroll
    for (int i = 0; i < 2; ++i) {
        const int chunk = i * 256 + t, row = chunk >> 3, c = chunk & 7;
        const int cs = c ^ (row & 7);
        async_copy16(kb + row * DK + cs * 8, &ktb[chunk * 8]);
        async_copy16(vb + row * SEQ + cs * 8, &vtb[chunk * 8]);
    }

    // qt staging (XOR-swizzled, plain vector loads): 128 rows
    #pragma unroll
    for (int i = 0; i < 4; ++i) {
        const int chunk = i * 256 + t, row = chunk >> 3, c = chunk & 7;
        const int cs = c ^ (row & 7);
        *(uint4*)&qt[chunk * 8] = *(const uint4*)&qb[(q0 + row) * DK + cs * 8];
    }
    for (int u = t; u < 639; u += 256) biasb[u] = rel[(q0 + u) * NH + h] * 1.44269504f;

    __syncthreads();   // qt/biasb visible; jt0 DMA drained

    // hoist jt-invariant Q fragments to registers (qt dead afterwards)
    bf16x8 aq[2][2];
    #pragma unroll
    for (int g = 0; g < 2; ++g) {
        const int ra = w * 32 + g * 16 + lm;
        aq[g][0] = *(const bf16x8*)&qt[ra * 64 + ((quad) ^ (ra & 7)) * 8];
        aq[g][1] = *(const bf16x8*)&qt[ra * 64 + ((4 + quad) ^ (ra & 7)) * 8];
    }
    __syncthreads();   // all waves hoisted; Pl may now overwrite qt region

    bf16x8 ones;
    #pragma unroll
    for (int i = 0; i < 8; ++i) ones[i] = (__bf16)1.0f;

    f32x4 ol[2];       // row-sum accumulators (all 4 components equal)
    f32x4 o[2][4];
    #pragma unroll
    for (int g = 0; g < 2; ++g) {
        ol[g] = (f32x4){0.f, 0.f, 0.f, 0.f};
        #pragma unroll
        for (int sd = 0; sd < 4; ++sd) o[g][sd] = (f32x4){0.f, 0.f, 0.f, 0.f};
    }

    const float scale2 = 0.125f * 1.44269504f;  // (1/sqrt(64)) * log2(e)

    for (int jt = 0; jt < 8; ++jt) {
        if (jt) __syncthreads();   // drains DMA for 'cur'; prior readers of 'nxt' done
        const int cur = jt & 1, nxt = cur ^ 1;
        u16* ktc = ktb + cur * 4096;
        u16* vtc = vtb + cur * 4096;
        if (jt < 7) {      // DMA next tile; overlaps compute below
            const int j1 = (jt + 1) * 64;
            u16* ktn = ktb + nxt * 4096;
            u16* vtn = vtb + nxt * 4096;
            #pragma unroll
            for (int i = 0; i < 2; ++i) {
                const int chunk = i * 256 + t, row = chunk >> 3, c = chunk & 7;
                const int cs = c ^ (row & 7);
                async_copy16(kb + (j1 + row) * DK + cs * 8, &ktn[chunk * 8]);
                async_copy16(vb + row * SEQ + j1 + cs * 8, &vtn[chunk * 8]);
            }
        }
        const int j0 = jt * 64;

        // ---- S^T = K·Q^T + exp2: lane owns q-row (g*16+lm), keys js*16+quad*4+r ----
        #pragma unroll
        for (int js = 0; js < 4; ++js) {
            const int rb = js * 16 + lm;
            bf16x8 bk0 = *(const bf16x8*)&ktc[rb * 64 + ((quad) ^ (rb & 7)) * 8];
            bf16x8 bk1 = *(const bf16x8*)&ktc[rb * 64 + ((4 + quad) ^ (rb & 7)) * 8];
            #pragma unroll
            for (int g = 0; g < 2; ++g) {
                f32x4 c = (f32x4){0.f, 0.f, 0.f, 0.f};
                c = __builtin_amdgcn_mfma_f32_16x16x32_bf16(bk0, aq[g][0], c, 0, 0, 0);
                c = __builtin_amdgcn_mfma_f32_16x16x32_bf16(bk1, aq[g][1], c, 0, 0, 0);
                const int bb0 = w * 32 + g * 16 + lm + 511 - j0 - js * 16 - quad * 4;
                float e0 = fexp2(c[0] * scale2 + biasb[bb0]);
                float e1 = fexp2(c[1] * scale2 + biasb[bb0 - 1]);
                float e2 = fexp2(c[2] * scale2 + biasb[bb0 - 2]);
                float e3 = fexp2(c[3] * scale2 + biasb[bb0 - 3]);
                uint2 pk = {cvtpk(e0, e1), cvtpk(e2, e3)};
                *(uint2*)&Pl[w][g * 16 + lm][js * 16 + quad * 4] = pk;  // one b64 write
            }
        }

        // ---- O^T += V^T · P^T ; lsum += ones · P^T  (wave-private P, no barrier) ----
        bf16x8 ap[2][2];
        #pragma unroll
        for (int g = 0; g < 2; ++g) {
            ap[g][0] = *(const bf16x8*)&Pl[w][g * 16 + lm][quad * 8];        // keys 0..31
            ap[g][1] = *(const bf16x8*)&Pl[w][g * 16 + lm][32 + quad * 8];   // keys 32..63
            ol[g] = __builtin_amdgcn_mfma_f32_16x16x32_bf16(ones, ap[g][0], ol[g], 0, 0, 0);
            ol[g] = __builtin_amdgcn_mfma_f32_16x16x32_bf16(ones, ap[g][1], ol[g], 0, 0, 0);
        }
        #pragma unroll
        for (int sd = 0; sd < 4; ++sd) {
            const int rv = sd * 16 + lm;
            bf16x8 bv0 = *(const bf16x8*)&vtc[rv * 64 + ((quad) ^ (rv & 7)) * 8];
            bf16x8 bv1 = *(const bf16x8*)&vtc[rv * 64 + ((4 + quad) ^ (rv & 7)) * 8];
            #pragma unroll
            for (int g = 0; g < 2; ++g) {
                o[g][sd] = __builtin_amdgcn_mfma_f32_16x16x32_bf16(bv0, ap[g][0], o[g][sd], 0, 0, 0);
                o[g][sd] = __builtin_amdgcn_mfma_f32_16x16x32_bf16(bv1, ap[g][1], o[g][sd], 0, 0, 0);
            }
        }
    }

    // ---- epilogue: normalize lane-locally (ol holds row-sum), transpose, store ----
    #pragma unroll
    for (int g = 0; g < 2; ++g) {
        const float rinv = 1.0f / ol[g][0];
        #pragma unroll
        for (int sd = 0; sd < 4; ++sd) {
            uint2 pk = {cvtpk(o[g][sd][0] * rinv, o[g][sd][1] * rinv),
                        cvtpk(o[g][sd][2] * rinv, o[g][sd][3] * rinv)};
            *(uint2*)&Pl[w][g * 16 + lm][sd * 16 + quad * 4] = pk;   // O rows = q_rel
        }
    }
    const int rowl = lane >> 1, ch = lane & 1;   // 32 rows x 2 chunks of 64B per wave
    u16* dp = aout + (size_t)(b * SEQ + q0 + w * 32 + rowl) * D_MODEL + h * DK + ch * 32;
    #pragma unroll
    for (int c = 0; c < 4; ++c)
        *(uint4*)&dp[c * 8] = *(const uint4*)&Pl[w][rowl][ch * 32 + c * 8];
}

extern "C" void kernel_launch(void* const* d_in, const int* in_sizes, int n_in,
                              void* d_out, int out_size, void* d_ws, size_t ws_size,
                              hipStream_t stream) {
    const float* x   = (const float*)d_in[0];
    const float* Wq  = (const float*)d_in[2];
    const float* bq  = (const float*)d_in[3];
    const float* Wk  = (const float*)d_in[4];
    const float* bk  = (const float*)d_in[5];
    const float* Wv  = (const float*)d_in[6];
    const float* bv  = (const float*)d_in[7];
    const float* Wo  = (const float*)d_in[8];
    const float* bo  = (const float*)d_in[9];
    const float* rel = (const float*)d_in[10];
    float* out = (float*)d_out;

    u16* ws = (u16*)d_ws;
    const size_t WSZ = (size_t)D_MODEL * D_MODEL;   // 1M u16 (2 MB)
    const size_t TSZ = (size_t)M_TOT * D_MODEL;     // 8M u16 (16 MB)
    u16* Wt3 = ws;            // 6 MB (qkv concat); slab0 reused for Wo^T (written by attn tail)
    u16* xbf = Wt3 + 3 * WSZ;
    u16* qws = xbf + TSZ;
    u16* kws = qws + TSZ;
    u16* vws = kws + TSZ;     // stored transposed [b,h,d,s]
    u16* aws = xbf;           // xbf dead after qkv GEMM; attn out FLAT [M, D_MODEL]

    dim3 tb(256);
    prep<<<dim3(2048 + 768), tb, 0, stream>>>(x, xbf, Wq, Wk, Wv, Wt3);
    gemm_bt<<<dim3(24, 64), tb, 0, stream>>>(xbf, Wt3, bq, bk, bv, qws, kws, vws, 1);
    attn_flash<<<dim3(1024 + 256), tb, 0, stream>>>(qws, kws, vws, rel, aws, Wo, Wt3);
    gemm_bt<<<dim3(8, 64), tb, 0, stream>>>(aws, Wt3, bo, nullptr, nullptr,
                                            (void*)out, nullptr, nullptr, 0);
}